// Round 5
// baseline (113.699 us; speedup 1.0000x reference)
//
#include <hip/hip_runtime.h>
#include <hip/hip_bf16.h>

// Chamfer distance, B=16, N=M=4096, D=3, fp32 — one-pass MFMA, both mins.
// Round-5: 4-MFMA steps, single-shot staging, spill-aware register layout.
//
// Post-mortem lineage: rounds 1-2's "ws pathology" (GB-scale scratch
// traffic) was VGPR SPILL from 4 live float16 accumulators; rounds 3-4
// avoided it but paid 2-MFMA steps (per-step overhead dominated). This
// version: 4 MFMAs/step sequenced as TWO PAIRS so only 2 float16 results
// are ever live (~105 VGPR < 128 cap @ 4 waves/EU).
//
// Block = 256 rows x 1024 cols (grid: q4 x b16 x strip16 = 1024 = 4/CU).
// Stage once (no dbuf, no chunk loop): 1024 tgt pts -> bf16 hi/lo frags in
// 32KB LDS; colpart 4KB; 36KB total -> 4 blocks/CU. 16 j-steps of:
//   prefetch next frags -> [pair0: 2 MFMA + rm0-min3 + trees] ->
//   [pair1: 2 MFMA + rm1-min3 + trees] -> 2 LDS atomicMin (64-lane atomic
//   merges h-halves AND row-groups; the old per-step shfl was redundant).
//   row-min -> cham_x : rm[2][16] accum + cross-lane fold -> wsR atomicMin
//   col-min -> cham_y : clamped uint atomicMin colpart -> wsC atomicMin
// finish: ONE 1024-thread block sums both 256KB planes, plain-stores out.
// 3 dispatches total (memset ws, main, finish).

#define BATCH   16
#define NPTS    4096
#define NSTRIPS 16                 // 256 rows per block
#define NQ      4                  // col quarters, 1024 cols per block
#define COLS_PB 1024
#define NSTEP   (COLS_PB / 64)     // 16

typedef __attribute__((ext_vector_type(8)))  short short8;
typedef __attribute__((ext_vector_type(16))) float float16;

union U4S8 { uint4 u; short8 s; };

__device__ inline unsigned int bfb(float v) {
    __hip_bfloat16 h = __float2bfloat16(v);
    unsigned short u; __builtin_memcpy(&u, &h, 2);
    return (unsigned int)u;
}
__device__ inline float bff(float v) { return __bfloat162float(__float2bfloat16(v)); }

#define ONEB 0x3F80u

// A (query) slots: [xh yh zh xh yh zh xl yl | zl fh fl 1 1 0 0 0]
__device__ inline void buildA(float x, float y, float z, uint4& w0, uint4& w1) {
    float xhf = bff(x), yhf = bff(y), zhf = bff(z);
    float f = fmaf(x, x, fmaf(y, y, z * z));
    float fhf = bff(f);
    unsigned xh = bfb(xhf), yh = bfb(yhf), zh = bfb(zhf);
    unsigned xl = bfb(x - xhf), yl = bfb(y - yhf), zl = bfb(z - zhf);
    unsigned fh = bfb(fhf), fl = bfb(f - fhf);
    w0 = make_uint4(xh | (yh << 16), zh | (xh << 16),
                    yh | (zh << 16), xl | (yl << 16));
    w1 = make_uint4(zl | (fh << 16), fl | (ONEB << 16), ONEB, 0u);
}

// B (target) slots: [-2xh -2yh -2zh -2xl -2yl -2zl -2xh -2yh | -2zh 1 1 fh fl 0 0 0]
__device__ inline void buildB(float x, float y, float z, uint4& w0, uint4& w1) {
    float xhf = bff(x), yhf = bff(y), zhf = bff(z);
    float f = fmaf(x, x, fmaf(y, y, z * z));
    float fhf = bff(f);
    unsigned a = bfb(-2.0f * xhf), b = bfb(-2.0f * yhf), c = bfb(-2.0f * zhf);
    unsigned d = bfb(-2.0f * (x - xhf)), e = bfb(-2.0f * (y - yhf)),
             g = bfb(-2.0f * (z - zhf));
    unsigned fh = bfb(fhf), fl = bfb(f - fhf);
    w0 = make_uint4(a | (b << 16), c | (d << 16),
                    e | (g << 16), a | (b << 16));
    w1 = make_uint4(c | (ONEB << 16), ONEB | (fh << 16), fl, 0u);
}

// min over the 16 regs (this half's 16 rows) of one 32x32 MFMA result.
__device__ inline float tree16(const float16& a) {
    float m0 = fminf(fminf(a[0],  a[1]),  a[2]);    // v_min3
    float m1 = fminf(fminf(a[3],  a[4]),  a[5]);
    float m2 = fminf(fminf(a[6],  a[7]),  a[8]);
    float m3 = fminf(fminf(a[9],  a[10]), a[11]);
    float m4 = fminf(fminf(a[12], a[13]), a[14]);
    float p0 = fminf(fminf(m0, m1), a[15]);
    float p1 = fminf(fminf(m2, m3), m4);
    return fminf(p0, p1);
}

__global__ __launch_bounds__(256, 4) void chamfer_main(
    const float* __restrict__ src, const float* __restrict__ tgt,
    unsigned* __restrict__ wsC, unsigned* __restrict__ wsR)
{
    __shared__ uint4 sbuf[2][COLS_PB];      // [half][pt] = 32 KB
    __shared__ unsigned colpart[COLS_PB];   // 4 KB (rows reuse [0:256))

    int blk = blockIdx.x;
    const int strip = blk & (NSTRIPS - 1); blk >>= 4;
    const int b     = blk & 15;            blk >>= 4;
    const int q     = blk;                 // col quarter 0..3
    const int qoff  = q * COLS_PB;

    const int t    = threadIdx.x;
    const int lane = t & 63;
    const int w    = t >> 6;
    const int h    = lane >> 5;
    const int l5   = lane & 31;

    const float* Araw = src + (size_t)b * NPTS * 3;   // rows (queries)
    const float* Braw = tgt + (size_t)b * NPTS * 3;   // cols (targets)

    // raw loads for this block's 1024 cols (issue all early)
    float nx[4][3];
#pragma unroll
    for (int k = 0; k < 4; k++) {
        int p = qoff + t + k * 256;
        nx[k][0] = Braw[3 * p + 0];
        nx[k][1] = Braw[3 * p + 1];
        nx[k][2] = Braw[3 * p + 2];
    }

    // A fragments: 2 row-groups of 32 per wave (256 rows per block)
    short8 afr[2];
#pragma unroll
    for (int g = 0; g < 2; g++) {
        int row = strip * 256 + g * 128 + w * 32 + l5;
        uint4 w0, w1;
        buildA(Araw[3 * row], Araw[3 * row + 1], Araw[3 * row + 2], w0, w1);
        U4S8 tt; tt.u = h ? w1 : w0;
        afr[g] = tt.s;
    }

    // init block-local col-min plane (4 per thread)
#pragma unroll
    for (int i = 0; i < COLS_PB / 256; i++) colpart[t + i * 256] = 0xFFFFFFFFu;

    // convert + stage B fragments (once; no chunk loop)
#pragma unroll
    for (int k = 0; k < 4; k++) {
        int lp = t + k * 256;
        uint4 w0, w1;
        buildB(nx[k][0], nx[k][1], nx[k][2], w0, w1);
        sbuf[0][lp] = w0;
        sbuf[1][lp] = w1;
    }
    __syncthreads();

    const float16 z16 = {0.f,0.f,0.f,0.f,0.f,0.f,0.f,0.f,
                         0.f,0.f,0.f,0.f,0.f,0.f,0.f,0.f};
    float rm[2][16];
#pragma unroll
    for (int g = 0; g < 2; g++)
#pragma unroll
        for (int r = 0; r < 16; r++) rm[g][r] = 1e30f;

    U4S8 c0, c1, n0, n1;
    c0.u = sbuf[h][l5];
    c1.u = sbuf[h][32 + l5];
#pragma unroll 4
    for (int j = 0; j < NSTEP; j++) {
        int nj = (j + 1) & (NSTEP - 1);           // wrap re-read: harmless
        n0.u = sbuf[h][nj * 64 + l5];
        n1.u = sbuf[h][nj * 64 + 32 + l5];

        // pair 0: row-group 0 (only 2 float16 results live at any time)
        float t0, t1;
        {
            float16 a0 = __builtin_amdgcn_mfma_f32_32x32x16_bf16(afr[0], c0.s, z16, 0, 0, 0);
            float16 a1 = __builtin_amdgcn_mfma_f32_32x32x16_bf16(afr[0], c1.s, z16, 0, 0, 0);
#pragma unroll
            for (int r = 0; r < 16; r++)
                rm[0][r] = fminf(fminf(a0[r], a1[r]), rm[0][r]);   // v_min3
            t0 = tree16(a0);
            t1 = tree16(a1);
        }
        // pair 1: row-group 1 (reuses the result registers)
        {
            float16 a0 = __builtin_amdgcn_mfma_f32_32x32x16_bf16(afr[1], c0.s, z16, 0, 0, 0);
            float16 a1 = __builtin_amdgcn_mfma_f32_32x32x16_bf16(afr[1], c1.s, z16, 0, 0, 0);
#pragma unroll
            for (int r = 0; r < 16; r++)
                rm[1][r] = fminf(fminf(a0[r], a1[r]), rm[1][r]);
            t0 = fminf(t0, tree16(a0));
            t1 = fminf(t1, tree16(a1));
        }
        // 64-lane LDS atomicMin merges h-halves and row-groups (no shfl).
        const int col = j * 64 + l5;
        atomicMin(&colpart[col],      __float_as_uint(fmaxf(t0, 0.0f)));
        atomicMin(&colpart[col + 32], __float_as_uint(fmaxf(t1, 0.0f)));
        c0 = n0; c1 = n1;
    }

    // merge block-local col-mins into the global plane (4 per thread)
    __syncthreads();
#pragma unroll
    for (int i = 0; i < COLS_PB / 256; i++) {
        const int idx = t + i * 256;
        atomicMin(&wsC[(size_t)b * NPTS + qoff + idx], colpart[idx]);
    }

    // Row-min partial (this block's 1024 cols): fold 32 col-slots across
    // lanes (masks 1..16; h-halves hold disjoint row sets -> no mask 32).
#pragma unroll
    for (int mask = 1; mask <= 16; mask <<= 1)
#pragma unroll
        for (int g = 0; g < 2; g++)
#pragma unroll
            for (int r = 0; r < 16; r++)
                rm[g][r] = fminf(rm[g][r], __shfl_xor(rm[g][r], mask, 64));

    // transpose via LDS (reuse colpart[0:256) after its merge), coalesced
    // clamped atomicMin into wsR.
    __syncthreads();                 // colpart merge reads done
    if (l5 == 0) {
#pragma unroll
        for (int g = 0; g < 2; g++)
#pragma unroll
            for (int r = 0; r < 16; r++) {
                const int row = g * 128 + w * 32 + (r & 3) + 8 * (r >> 2) + 4 * h;
                colpart[row] = __float_as_uint(fmaxf(rm[g][r], 0.0f));
            }
    }
    __syncthreads();
    atomicMin(&wsR[(size_t)b * NPTS + strip * 256 + t], colpart[t]);
}

// ------------- finish: ONE block sums both 256KB planes, stores out
__global__ __launch_bounds__(1024) void finish_reduce(
    const unsigned* __restrict__ ws, float* __restrict__ out)
{
    __shared__ float wsum[16];
    const int t = threadIdx.x;
    float v = 0.0f;
#pragma unroll
    for (int i = 0; i < 2 * BATCH * NPTS / 1024; i++)      // 128 loads
        v += __uint_as_float(ws[t + i * 1024]);
#pragma unroll
    for (int mask = 1; mask <= 32; mask <<= 1) v += __shfl_xor(v, mask, 64);
    if ((t & 63) == 0) wsum[t >> 6] = v;
    __syncthreads();
    if (t < 64) {
        float s = (t < 16) ? wsum[t] : 0.0f;
#pragma unroll
        for (int mask = 1; mask <= 8; mask <<= 1) s += __shfl_xor(s, mask, 64);
        if (t == 0) out[0] = s * (1.0f / (float)NPTS);
    }
}

// ---------------------------------------------------------------- launch
extern "C" void kernel_launch(void* const* d_in, const int* in_sizes, int n_in,
                              void* d_out, int out_size, void* d_ws, size_t ws_size,
                              hipStream_t stream)
{
    const float* src = (const float*)d_in[0];
    const float* tgt = (const float*)d_in[1];
    float* out = (float*)d_out;
    unsigned* wsC = (unsigned*)d_ws;                      // 256 KB
    unsigned* wsR = wsC + (size_t)BATCH * NPTS;           // 256 KB

    hipMemsetAsync(d_ws, 0xFF, (size_t)2 * BATCH * NPTS * sizeof(unsigned), stream);
    chamfer_main <<<NQ * BATCH * NSTRIPS, 256, 0, stream>>>(src, tgt, wsC, wsR);
    finish_reduce<<<1, 1024, 0, stream>>>(wsC, out);
}

// Round 6
// 106.324 us; speedup vs baseline: 1.0694x; 1.0694x over previous
//
#include <hip/hip_runtime.h>
#include <hip/hip_bf16.h>

// Chamfer distance, B=16, N=M=4096, D=3, fp32 — one-pass MFMA, both mins.
// Round-6: LDS-pipe diet on the round-4 skeleton.
//
// Empirical rules from rounds 0-5 (6-for-6 consistent):
//  * SPILL RULE: one row-group per wave (rm[16]) at __launch_bounds__(256,4).
//    Any kernel with rm[2+][16] + live float16 results under a <=170 VGPR
//    cap hit GB-scale scratch traffic (r1: 525us, r2: 335us, r5: +35us).
//  * Round-4 (best one-pass, ~27us main) was LDS-PIPE bound: ds_reads 12.3k
//    + colliding LDS atomics ~24k + 320 end-fold ds_swizzles ~15k cyc/CU.
// This round cuts the last two:
//  1) colpart2[h][col]: lanes l5 / l5+32 hit DIFFERENT addresses -> no
//     intra-instruction same-address serialization on atomicMin.
//  2) row-min fold via XOR-swizzled LDS transpose (plain writes + 32 b32
//     conflict-free reads + 31 fmin) instead of 5x16 __shfl_xor.
//  3) single-buffer sbuf 16KB (512-col chunks) so LDS = 32.8KB -> 4 blk/CU.
// Grid: q(2 col-halves) x b(16) x strip(32) = 1024 blocks x 256 thr.
// Block = 128 rows x 2048 cols; 4 chunks x 8 steps; per step: 2 ds_read ->
// 2 MFMA -> 16 rm-min3 -> 2 tree16 -> 2 collision-free LDS atomicMin.
// End: colpart2 merge -> wsC (global atomicMin), rm transpose -> wsR.
// finish: ONE 1024-thread block sums both 256KB planes, plain-stores out.
// 3 dispatches (memset ws, main, finish).

#define BATCH   16
#define NPTS    4096
#define NSTRIPS 32                 // 128 rows per block
#define NQ      2                  // col halves
#define COLS_PB 2048
#define CHUNKC  512
#define NCHUNKS (COLS_PB / CHUNKC) // 4
#define NSTEP   (CHUNKC / 64)      // 8

typedef __attribute__((ext_vector_type(8)))  short short8;
typedef __attribute__((ext_vector_type(16))) float float16;

union U4S8 { uint4 u; short8 s; };

__device__ inline unsigned int bfb(float v) {
    __hip_bfloat16 h = __float2bfloat16(v);
    unsigned short u; __builtin_memcpy(&u, &h, 2);
    return (unsigned int)u;
}
__device__ inline float bff(float v) { return __bfloat162float(__float2bfloat16(v)); }

#define ONEB 0x3F80u

// A (query) slots: [xh yh zh xh yh zh xl yl | zl fh fl 1 1 0 0 0]
__device__ inline void buildA(float x, float y, float z, uint4& w0, uint4& w1) {
    float xhf = bff(x), yhf = bff(y), zhf = bff(z);
    float f = fmaf(x, x, fmaf(y, y, z * z));
    float fhf = bff(f);
    unsigned xh = bfb(xhf), yh = bfb(yhf), zh = bfb(zhf);
    unsigned xl = bfb(x - xhf), yl = bfb(y - yhf), zl = bfb(z - zhf);
    unsigned fh = bfb(fhf), fl = bfb(f - fhf);
    w0 = make_uint4(xh | (yh << 16), zh | (xh << 16),
                    yh | (zh << 16), xl | (yl << 16));
    w1 = make_uint4(zl | (fh << 16), fl | (ONEB << 16), ONEB, 0u);
}

// B (target) slots: [-2xh -2yh -2zh -2xl -2yl -2zl -2xh -2yh | -2zh 1 1 fh fl 0 0 0]
__device__ inline void buildB(float x, float y, float z, uint4& w0, uint4& w1) {
    float xhf = bff(x), yhf = bff(y), zhf = bff(z);
    float f = fmaf(x, x, fmaf(y, y, z * z));
    float fhf = bff(f);
    unsigned a = bfb(-2.0f * xhf), b = bfb(-2.0f * yhf), c = bfb(-2.0f * zhf);
    unsigned d = bfb(-2.0f * (x - xhf)), e = bfb(-2.0f * (y - yhf)),
             g = bfb(-2.0f * (z - zhf));
    unsigned fh = bfb(fhf), fl = bfb(f - fhf);
    w0 = make_uint4(a | (b << 16), c | (d << 16),
                    e | (g << 16), a | (b << 16));
    w1 = make_uint4(c | (ONEB << 16), ONEB | (fh << 16), fl, 0u);
}

// min over the 16 regs (this half's 16 rows) of one 32x32 MFMA result.
__device__ inline float tree16(const float16& a) {
    float m0 = fminf(fminf(a[0],  a[1]),  a[2]);    // v_min3
    float m1 = fminf(fminf(a[3],  a[4]),  a[5]);
    float m2 = fminf(fminf(a[6],  a[7]),  a[8]);
    float m3 = fminf(fminf(a[9],  a[10]), a[11]);
    float m4 = fminf(fminf(a[12], a[13]), a[14]);
    float p0 = fminf(fminf(m0, m1), a[15]);
    float p1 = fminf(fminf(m2, m3), m4);
    return fminf(p0, p1);
}

__global__ __launch_bounds__(256, 4) void chamfer_main(
    const float* __restrict__ src, const float* __restrict__ tgt,
    unsigned* __restrict__ wsC, unsigned* __restrict__ wsR)
{
    __shared__ uint4     sbuf[2][CHUNKC];      // [half][pt] = 16 KB
    __shared__ unsigned  colpart2[2][COLS_PB]; // 16 KB; reused as rowbuf later

    int blk = blockIdx.x;
    const int strip = blk & (NSTRIPS - 1); blk >>= 5;
    const int b     = blk & 15;            blk >>= 4;
    const int q     = blk;                 // col half 0/1
    const int qoff  = q * COLS_PB;

    const int t    = threadIdx.x;
    const int lane = t & 63;
    const int w    = t >> 6;
    const int h    = lane >> 5;
    const int l5   = lane & 31;

    const float* Araw = src + (size_t)b * NPTS * 3;   // rows (queries)
    const float* Braw = tgt + (size_t)b * NPTS * 3;   // cols (targets)

    // A fragment: one 32-row group per wave (128 rows per block). SPILL RULE.
    short8 afr;
    {
        int row = strip * 128 + w * 32 + l5;
        uint4 w0, w1;
        buildA(Araw[3 * row], Araw[3 * row + 1], Araw[3 * row + 2], w0, w1);
        U4S8 tt; tt.u = h ? w1 : w0;
        afr = tt.s;
    }

    // init col-min planes (16 cells = 1 uint4 x 4 per thread)
    {
        uint4* cp = (uint4*)&colpart2[0][0];
#pragma unroll
        for (int i = 0; i < 4; i++)
            cp[t + i * 256] = make_uint4(0xFFFFFFFFu, 0xFFFFFFFFu,
                                         0xFFFFFFFFu, 0xFFFFFFFFu);
    }

    float nx[2][3];
    auto loadRaw = [&](int c) {
#pragma unroll
        for (int k = 0; k < 2; k++) {
            int p = qoff + c * CHUNKC + t + k * 256;
            nx[k][0] = Braw[3 * p + 0];
            nx[k][1] = Braw[3 * p + 1];
            nx[k][2] = Braw[3 * p + 2];
        }
    };
    auto convertWrite = [&]() {
#pragma unroll
        for (int k = 0; k < 2; k++) {
            int lp = t + k * 256;
            uint4 w0, w1;
            buildB(nx[k][0], nx[k][1], nx[k][2], w0, w1);
            sbuf[0][lp] = w0;
            sbuf[1][lp] = w1;
        }
    };

    const float16 z16 = {0.f,0.f,0.f,0.f,0.f,0.f,0.f,0.f,
                         0.f,0.f,0.f,0.f,0.f,0.f,0.f,0.f};
    float rm[16];
#pragma unroll
    for (int r = 0; r < 16; r++) rm[r] = 1e30f;

    loadRaw(0);
    for (int c = 0; c < NCHUNKS; c++) {
        if (c) __syncthreads();            // prior chunk's reads complete
        convertWrite();
        __syncthreads();                   // sbuf visible (also covers init)
        if (c + 1 < NCHUNKS) loadRaw(c + 1);   // issue, don't wait

        U4S8 c0, c1, n0, n1;
        c0.u = sbuf[h][l5];
        c1.u = sbuf[h][32 + l5];
#pragma unroll 4
        for (int j = 0; j < NSTEP; j++) {
            int nj = (j + 1) & (NSTEP - 1);        // wrap re-read: harmless
            n0.u = sbuf[h][nj * 64 + l5];
            n1.u = sbuf[h][nj * 64 + 32 + l5];
            float16 a0 = __builtin_amdgcn_mfma_f32_32x32x16_bf16(afr, c0.s, z16, 0, 0, 0);
            float16 a1 = __builtin_amdgcn_mfma_f32_32x32x16_bf16(afr, c1.s, z16, 0, 0, 0);
#pragma unroll
            for (int r = 0; r < 16; r++)
                rm[r] = fminf(fminf(a0[r], a1[r]), rm[r]);     // v_min3
            // col-mins over this half's 16 rows; [h]-split planes make the
            // two halves' atomics collision-free within the instruction.
            float cm0 = tree16(a0);
            float cm1 = tree16(a1);
            const int col = c * CHUNKC + j * 64 + l5;
            atomicMin(&colpart2[h][col],      __float_as_uint(fmaxf(cm0, 0.0f)));
            atomicMin(&colpart2[h][col + 32], __float_as_uint(fmaxf(cm1, 0.0f)));
            c0 = n0; c1 = n1;
        }
    }
    __syncthreads();                       // all col atomics visible

    // merge the two half-planes -> global col plane (8 cols per thread)
#pragma unroll
    for (int i = 0; i < COLS_PB / 256; i++) {
        const int col = t + i * 256;
        unsigned v = min(colpart2[0][col], colpart2[1][col]);
        atomicMin(&wsC[(size_t)b * NPTS + qoff + col], v);
    }
    __syncthreads();                       // colpart2 dead; reuse as rowbuf

    // Row-min fold via XOR-bank-swizzled transpose (no shfl storm).
    // rowbuf[w][rl][c] at flat dword (w*32+rl)*32 + (c ^ rl); 16 KB overlay.
    float* rowbuf = (float*)&colpart2[0][0];
#pragma unroll
    for (int r = 0; r < 16; r++) {
        const int rl = (r & 3) + 8 * (r >> 2) + 4 * h;   // 0..31 in wave rows
        rowbuf[(w * 32 + rl) * 32 + (l5 ^ rl)] = rm[r];
    }
    __syncthreads();
    if (t < 128) {                         // thread t owns block row t
        const int rl = t & 31;
        float m = 1e30f;
#pragma unroll
        for (int cc = 0; cc < 32; cc++)
            m = fminf(m, rowbuf[t * 32 + (cc ^ rl)]);
        atomicMin(&wsR[(size_t)b * NPTS + strip * 128 + t],
                  __float_as_uint(fmaxf(m, 0.0f)));
    }
}

// ------------- finish: ONE block sums both 256KB planes, stores out
__global__ __launch_bounds__(1024) void finish_reduce(
    const unsigned* __restrict__ ws, float* __restrict__ out)
{
    __shared__ float wsum[16];
    const int t = threadIdx.x;
    float v = 0.0f;
#pragma unroll
    for (int i = 0; i < 2 * BATCH * NPTS / 1024; i++)      // 128 loads
        v += __uint_as_float(ws[t + i * 1024]);
#pragma unroll
    for (int mask = 1; mask <= 32; mask <<= 1) v += __shfl_xor(v, mask, 64);
    if ((t & 63) == 0) wsum[t >> 6] = v;
    __syncthreads();
    if (t < 64) {
        float s = (t < 16) ? wsum[t] : 0.0f;
#pragma unroll
        for (int mask = 1; mask <= 8; mask <<= 1) s += __shfl_xor(s, mask, 64);
        if (t == 0) out[0] = s * (1.0f / (float)NPTS);
    }
}

// ---------------------------------------------------------------- launch
extern "C" void kernel_launch(void* const* d_in, const int* in_sizes, int n_in,
                              void* d_out, int out_size, void* d_ws, size_t ws_size,
                              hipStream_t stream)
{
    const float* src = (const float*)d_in[0];
    const float* tgt = (const float*)d_in[1];
    float* out = (float*)d_out;
    unsigned* wsC = (unsigned*)d_ws;                      // 256 KB
    unsigned* wsR = wsC + (size_t)BATCH * NPTS;           // 256 KB

    hipMemsetAsync(d_ws, 0xFF, (size_t)2 * BATCH * NPTS * sizeof(unsigned), stream);
    chamfer_main <<<NQ * BATCH * NSTRIPS, 256, 0, stream>>>(src, tgt, wsC, wsR);
    finish_reduce<<<1, 1024, 0, stream>>>(wsC, out);
}